// Round 3
// baseline (217.944 us; speedup 1.0000x reference)
//
#include <hip/hip_runtime.h>

// ---- C[M,N] = A[M,K] @ B^T, B rows selected per 64-wide column tile ----
__global__ __launch_bounds__(256) void gemm_abt(
    const float* __restrict__ A, const float* __restrict__ B0,
    const float* __restrict__ B1, const float* __restrict__ B2,
    int n1, int n2, float* __restrict__ C, int N, int K) {
  __shared__ __align__(16) float As[16 * 68];
  __shared__ __align__(16) float Bs[16 * 68];
  const int m0 = blockIdx.y * 64;
  const int n0 = blockIdx.x * 64;
  const float* B = B0;
  int bn = n0;
  if (n0 >= n2)      { B = B2; bn = n0 - n2; }
  else if (n0 >= n1) { B = B1; bn = n0 - n1; }
  const int tid = threadIdx.x;
  const int tx = tid & 15, ty = tid >> 4;
  float acc[4][4] = {};
  for (int kb = 0; kb < K; kb += 16) {
    __syncthreads();
#pragma unroll
    for (int r = 0; r < 4; ++r) {
      int e = r * 256 + tid;
      int ar = e >> 4, ac = e & 15;
      As[ac * 68 + ar] = A[(m0 + ar) * K + kb + ac];
      Bs[ac * 68 + ar] = B[(bn + ar) * K + kb + ac];
    }
    __syncthreads();
#pragma unroll
    for (int kk = 0; kk < 16; ++kk) {
      float4 av = *(const float4*)&As[kk * 68 + ty * 4];
      float4 bv = *(const float4*)&Bs[kk * 68 + tx * 4];
      float a[4] = {av.x, av.y, av.z, av.w};
      float b[4] = {bv.x, bv.y, bv.z, bv.w};
#pragma unroll
      for (int i = 0; i < 4; ++i)
#pragma unroll
        for (int j = 0; j < 4; ++j) acc[i][j] += a[i] * b[j];
    }
  }
#pragma unroll
  for (int i = 0; i < 4; ++i) {
    float4 o = make_float4(acc[i][0], acc[i][1], acc[i][2], acc[i][3]);
    *(float4*)&C[(m0 + ty * 4 + i) * N + n0 + tx * 4] = o;
  }
}

// ---- direct causal taylor attention, per (chunk, head) block ----
// sc(t,s) = phi(q_t).phi(k_s) = 1 + (q.k)/4 + (q.k)^2/32  (exact identity)
// num[t,d] = sum_{s<=t} sc*v[s,d]; den[t] = sum_{s<=t} sc; y = num/den.
__global__ __launch_bounds__(256) void attn_direct(
    const float* __restrict__ QKV, float* __restrict__ Y) {
  const int c = blockIdx.x, h = blockIdx.y, tid = threadIdx.x;
  __shared__ __align__(16) float ql[64 * 17];
  __shared__ __align__(16) float kl[64 * 17];
  __shared__ __align__(16) float vl[64 * 68];
  __shared__ __align__(16) float sc[64 * 68];
  __shared__ __align__(16) float denp[256];
  __shared__ __align__(16) float den_f[64];
  const int t0 = c * 64;
  for (int e = tid; e < 1024; e += 256) {
    int t = e >> 4, f = e & 15;
    ql[t * 17 + f] = QKV[(t0 + t) * 1152 + h * 16 + f];
  }
  const int tg = tid >> 4, dg = tid & 15;
  const int dt = tid & 63, dq = tid >> 6;
  float acc[4][4] = {};
  float dpart = 0.f;
  for (int sb = 0; sb <= c; ++sb) {
    const int s0 = sb * 64;
    __syncthreads();  // protect kl/vl/sc from previous iteration's readers
    for (int e = tid; e < 1024; e += 256) {
      int t = e >> 4, f = e & 15;
      kl[t * 17 + f] = QKV[(s0 + t) * 1152 + 192 + h * 16 + f];
    }
    for (int e = tid; e < 4096; e += 256) {
      int s = e >> 6, d = e & 63;
      vl[s * 68 + d] = QKV[(s0 + s) * 1152 + 384 + h * 64 + d];
    }
    __syncthreads();
    for (int e = tid; e < 4096; e += 256) {
      int t = e >> 6, s = e & 63;
      float val = 0.f;
      if (s0 + s <= t0 + t) {
        float qk = 0.f;
#pragma unroll
        for (int f = 0; f < 16; ++f) qk += ql[t * 17 + f] * kl[s * 17 + f];
        val = 1.f + 0.25f * qk + 0.03125f * qk * qk;
      }
      sc[t * 68 + s] = val;
    }
    __syncthreads();
    for (int s = dq * 16; s < dq * 16 + 16; ++s) dpart += sc[dt * 68 + s];
    for (int s = 0; s < 64; ++s) {
      float4 vv = *(const float4*)&vl[s * 68 + dg * 4];
      float b[4] = {vv.x, vv.y, vv.z, vv.w};
#pragma unroll
      for (int i = 0; i < 4; ++i) {
        float scv = sc[(tg * 4 + i) * 68 + s];
#pragma unroll
        for (int j = 0; j < 4; ++j) acc[i][j] += scv * b[j];
      }
    }
  }
  denp[tid] = dpart;
  __syncthreads();
  if (tid < 64)
    den_f[tid] = denp[tid] + denp[tid + 64] + denp[tid + 128] + denp[tid + 192] + 1e-12f;
  __syncthreads();
#pragma unroll
  for (int i = 0; i < 4; ++i) {
    int t = tg * 4 + i;
    float inv = 1.f / den_f[t];
    float4 o = make_float4(acc[i][0] * inv, acc[i][1] * inv, acc[i][2] * inv, acc[i][3] * inv);
    *(float4*)&Y[(t0 + t) * 768 + h * 64 + dg * 4] = o;
  }
}

extern "C" void kernel_launch(void* const* d_in, const int* in_sizes, int n_in,
                              void* d_out, int out_size, void* d_ws, size_t ws_size,
                              hipStream_t stream) {
  const float* hs = (const float*)d_in[0];
  const float* Wq = (const float*)d_in[1];
  const float* Wk = (const float*)d_in[2];
  const float* Wv = (const float*)d_in[3];
  const float* Wo = (const float*)d_in[4];
  float* out = (float*)d_out;
  float* ws = (float*)d_ws;

  float* QKV = ws;            // 512*1152
  float* Y   = ws + 589824;   // 512*768

  // QKV = hs @ [Wq|Wk|Wv]^T  -> [512, 1152]
  gemm_abt<<<dim3(18, 8), 256, 0, stream>>>(hs, Wq, Wk, Wv, 192, 384, QKV, 1152, 768);
  // direct causal attention -> Y [512, 768]
  attn_direct<<<dim3(8, 12), 256, 0, stream>>>(QKV, Y);
  // out = y @ Wo^T
  gemm_abt<<<dim3(12, 8), 256, 0, stream>>>(Y, Wo, Wo, Wo, 1 << 30, 1 << 30, out, 768, 768);
}

// Round 4
// 175.403 us; speedup vs baseline: 1.2425x; 1.2425x over previous
//
#include <hip/hip_runtime.h>

// ---- zero the atomic accumulators (num + den), float4 granularity ----
__global__ __launch_bounds__(256) void zero_ws(float* __restrict__ p, int n4) {
  int i = blockIdx.x * 256 + threadIdx.x;
  if (i < n4) ((float4*)p)[i] = make_float4(0.f, 0.f, 0.f, 0.f);
}

// ---- C[M,N] = A[M,K] @ B^T, B rows selected per 64-wide column tile ----
// Tile 32(M) x 64(N), BK=32, 256 threads, 2x4 register tile.
__global__ __launch_bounds__(256) void gemm_abt(
    const float* __restrict__ A, const float* __restrict__ B0,
    const float* __restrict__ B1, const float* __restrict__ B2,
    int n1, int n2, float* __restrict__ C, int N, int K) {
  __shared__ __align__(16) float As[32 * 36];
  __shared__ __align__(16) float Bs[32 * 68];
  const int m0 = blockIdx.y * 32;
  const int n0 = blockIdx.x * 64;
  const float* B = B0;
  int bn = n0;
  if (n0 >= n2)      { B = B2; bn = n0 - n2; }
  else if (n0 >= n1) { B = B1; bn = n0 - n1; }
  const int tid = threadIdx.x;
  const int tx = tid & 15, ty = tid >> 4;
  float acc[2][4] = {};
  for (int kb = 0; kb < K; kb += 32) {
    __syncthreads();
    {
      int row = tid >> 3, c4 = (tid & 7) * 4;
      float4 a = *(const float4*)&A[(m0 + row) * K + kb + c4];
      As[(c4 + 0) * 36 + row] = a.x;
      As[(c4 + 1) * 36 + row] = a.y;
      As[(c4 + 2) * 36 + row] = a.z;
      As[(c4 + 3) * 36 + row] = a.w;
#pragma unroll
      for (int r = 0; r < 2; ++r) {
        int e = r * 256 + tid;
        int brow = e >> 3, bc4 = (e & 7) * 4;
        float4 b = *(const float4*)&B[(bn + brow) * K + kb + bc4];
        Bs[(bc4 + 0) * 68 + brow] = b.x;
        Bs[(bc4 + 1) * 68 + brow] = b.y;
        Bs[(bc4 + 2) * 68 + brow] = b.z;
        Bs[(bc4 + 3) * 68 + brow] = b.w;
      }
    }
    __syncthreads();
#pragma unroll
    for (int kk = 0; kk < 32; ++kk) {
      float2 av = *(const float2*)&As[kk * 36 + ty * 2];
      float4 bv = *(const float4*)&Bs[kk * 68 + tx * 4];
      float a[2] = {av.x, av.y};
      float b[4] = {bv.x, bv.y, bv.z, bv.w};
#pragma unroll
      for (int i = 0; i < 2; ++i)
#pragma unroll
        for (int j = 0; j < 4; ++j) acc[i][j] += a[i] * b[j];
    }
  }
#pragma unroll
  for (int i = 0; i < 2; ++i) {
    float4 o = make_float4(acc[i][0], acc[i][1], acc[i][2], acc[i][3]);
    *(float4*)&C[(m0 + ty * 2 + i) * N + n0 + tx * 4] = o;
  }
}

// ---- one (t-block, s-block, head) tile of causal taylor attention ----
// sc(t,s) = 1 + (q.k)/4 + (q.k)^2/32 ; partial num/den -> atomicAdd.
__global__ __launch_bounds__(256) void attn_partial(
    const float* __restrict__ QKV, float* __restrict__ numAcc,
    float* __restrict__ denAcc) {
  int p = blockIdx.x;
  const int h = blockIdx.y, tid = threadIdx.x;
  int c = 0;
  while (p >= c + 1) { p -= c + 1; ++c; }
  const int sb = p;
  __shared__ __align__(16) float ql[64 * 17];
  __shared__ __align__(16) float kl[64 * 17];
  __shared__ __align__(16) float vl[64 * 68];
  __shared__ __align__(16) float sc[64 * 68];
  __shared__ __align__(16) float denp[256];
  const int t0 = c * 64, s0 = sb * 64;
  for (int e = tid; e < 1024; e += 256) {
    int t = e >> 4, f = e & 15;
    ql[t * 17 + f] = QKV[(t0 + t) * 1152 + h * 16 + f];
    kl[t * 17 + f] = QKV[(s0 + t) * 1152 + 192 + h * 16 + f];
  }
  for (int e = tid; e < 4096; e += 256) {
    int s = e >> 6, d = e & 63;
    vl[s * 68 + d] = QKV[(s0 + s) * 1152 + 384 + h * 64 + d];
  }
  __syncthreads();
  const bool diag = (sb == c);
  for (int e = tid; e < 4096; e += 256) {
    int t = e >> 6, s = e & 63;
    float val = 0.f;
    if (!diag || s <= t) {
      float qk = 0.f;
#pragma unroll
      for (int f = 0; f < 16; ++f) qk += ql[t * 17 + f] * kl[s * 17 + f];
      val = 1.f + 0.25f * qk + 0.03125f * qk * qk;
    }
    sc[t * 68 + s] = val;
  }
  __syncthreads();
  // den partials: 4 threads per row t
  {
    const int dt = tid & 63, dq = tid >> 6;
    float dpart = 0.f;
    for (int s = dq * 16; s < dq * 16 + 16; ++s) dpart += sc[dt * 68 + s];
    denp[tid] = dpart;
  }
  // num partial: 4x4 per thread
  const int tg = tid >> 4, dg = tid & 15;
  float acc[4][4] = {};
  for (int s4 = 0; s4 < 16; ++s4) {
    float4 srow[4];
#pragma unroll
    for (int i = 0; i < 4; ++i)
      srow[i] = *(const float4*)&sc[(tg * 4 + i) * 68 + s4 * 4];
#pragma unroll
    for (int u = 0; u < 4; ++u) {
      float4 vv = *(const float4*)&vl[(s4 * 4 + u) * 68 + dg * 4];
      float b[4] = {vv.x, vv.y, vv.z, vv.w};
#pragma unroll
      for (int i = 0; i < 4; ++i) {
        float sv = ((const float*)&srow[i])[u];
#pragma unroll
        for (int j = 0; j < 4; ++j) acc[i][j] += sv * b[j];
      }
    }
  }
  __syncthreads();
  if (tid < 64) {
    float d = denp[tid] + denp[tid + 64] + denp[tid + 128] + denp[tid + 192];
    atomicAdd(&denAcc[(t0 + tid) * 12 + h], d);
  }
#pragma unroll
  for (int i = 0; i < 4; ++i) {
    int t = t0 + tg * 4 + i;
#pragma unroll
    for (int j = 0; j < 4; ++j)
      atomicAdd(&numAcc[t * 768 + h * 64 + dg * 4 + j], acc[i][j]);
  }
}

// ---- y = num / (den + eps) ----
__global__ __launch_bounds__(256) void finalize(
    const float* __restrict__ numAcc, const float* __restrict__ denAcc,
    float* __restrict__ Y) {
  int g = blockIdx.x * 256 + threadIdx.x;  // float4 index, 98304 total
  int t = g / 192;
  int rem = g - t * 192;
  int h = rem >> 4;
  float4 n = ((const float4*)numAcc)[g];
  float inv = 1.f / (denAcc[t * 12 + h] + 1e-12f);
  ((float4*)Y)[g] = make_float4(n.x * inv, n.y * inv, n.z * inv, n.w * inv);
}

extern "C" void kernel_launch(void* const* d_in, const int* in_sizes, int n_in,
                              void* d_out, int out_size, void* d_ws, size_t ws_size,
                              hipStream_t stream) {
  const float* hs = (const float*)d_in[0];
  const float* Wq = (const float*)d_in[1];
  const float* Wk = (const float*)d_in[2];
  const float* Wv = (const float*)d_in[3];
  const float* Wo = (const float*)d_in[4];
  float* out = (float*)d_out;
  float* ws = (float*)d_ws;

  float* QKV    = ws;             // 512*1152 = 589824
  float* numAcc = ws + 589824;    // 512*768  = 393216
  float* denAcc = ws + 983040;    // 512*12   = 6144
  float* Y      = ws + 989184;    // 512*768  = 393216

  // zero the atomic accumulators (num + den contiguous): 399360 floats
  zero_ws<<<dim3(390), 256, 0, stream>>>(numAcc, 99840);
  // QKV = hs @ [Wq|Wk|Wv]^T  -> [512, 1152]
  gemm_abt<<<dim3(18, 16), 256, 0, stream>>>(hs, Wq, Wk, Wv, 192, 384, QKV, 1152, 768);
  // causal taylor attention partials -> numAcc/denAcc
  attn_partial<<<dim3(36, 12), 256, 0, stream>>>(QKV, numAcc, denAcc);
  // y = num/den
  finalize<<<dim3(384), 256, 0, stream>>>(numAcc, denAcc, Y);
  // out = y @ Wo^T
  gemm_abt<<<dim3(12, 16), 256, 0, stream>>>(Y, Wo, Wo, Wo, 1 << 30, 1 << 30, out, 768, 768);
}

// Round 5
// 137.343 us; speedup vs baseline: 1.5869x; 1.2771x over previous
//
#include <hip/hip_runtime.h>

typedef short bf16x8 __attribute__((ext_vector_type(8)));
typedef float f32x4 __attribute__((ext_vector_type(4)));

__device__ __forceinline__ unsigned short f2bf(float f) {
  union { float f; unsigned int u; } v; v.f = f;
  unsigned int r = v.u + 0x7FFFu + ((v.u >> 16) & 1u);
  return (unsigned short)(r >> 16);
}

// ---- fused: cast hs/Wq/Wk/Wv/Wo to bf16 + zero num/den accumulators ----
__global__ __launch_bounds__(256) void prep(
    const float* __restrict__ hs, const float* __restrict__ Wq,
    const float* __restrict__ Wk, const float* __restrict__ Wv,
    const float* __restrict__ Wo, unsigned short* __restrict__ hsb,
    unsigned short* __restrict__ Wqkvb, unsigned short* __restrict__ Wob,
    float* __restrict__ numAcc) {
  int b = blockIdx.x;
  const float* src; unsigned short* dst; int base;
  if (b < 384)       { src = hs; dst = hsb;            base = b * 1024; }
  else if (b < 528)  { src = Wq; dst = Wqkvb;          base = (b - 384) * 1024; }
  else if (b < 672)  { src = Wk; dst = Wqkvb + 147456; base = (b - 528) * 1024; }
  else if (b < 1248) { src = Wv; dst = Wqkvb + 294912; base = (b - 672) * 1024; }
  else if (b < 1824) { src = Wo; dst = Wob;            base = (b - 1248) * 1024; }
  else {  // zero numAcc(393216) + denAcc(6144) = 399360 floats = 99840 float4
    int i = (b - 1824) * 256 + threadIdx.x;
    ((float4*)numAcc)[i] = make_float4(0.f, 0.f, 0.f, 0.f);
    return;
  }
  int i = base + threadIdx.x * 4;
  float4 x = *(const float4*)&src[i];
  ushort4 o;
  o.x = f2bf(x.x); o.y = f2bf(x.y); o.z = f2bf(x.z); o.w = f2bf(x.w);
  *(ushort4*)&dst[i] = o;
}

// ---- C[M,N] = A[M,K] @ B[N,K]^T via 16x16x32 bf16 MFMA, one tile/wave ----
// Block = 4 waves = 32x32 macro-tile. No LDS; inputs L2-resident.
__global__ __launch_bounds__(256) void gemm_mfma(
    const unsigned short* __restrict__ A, const unsigned short* __restrict__ B,
    float* __restrict__ C, int N, int K) {
  const int tid = threadIdx.x;
  const int w = tid >> 6, lane = tid & 63;
  const int lm = lane & 15, quad = lane >> 4;
  const int mt = blockIdx.y * 32 + (w >> 1) * 16;
  const int nt = blockIdx.x * 32 + (w & 1) * 16;
  const unsigned short* a_ptr = A + (mt + lm) * K + quad * 8;
  const unsigned short* b_ptr = B + (nt + lm) * K + quad * 8;
  f32x4 acc = {0.f, 0.f, 0.f, 0.f};
#pragma unroll 4
  for (int kb = 0; kb < K; kb += 32) {
    bf16x8 av = *(const bf16x8*)(a_ptr + kb);
    bf16x8 bv = *(const bf16x8*)(b_ptr + kb);
    acc = __builtin_amdgcn_mfma_f32_16x16x32_bf16(av, bv, acc, 0, 0, 0);
  }
#pragma unroll
  for (int r = 0; r < 4; ++r)
    C[(mt + quad * 4 + r) * N + nt + lm] = acc[r];
}

// ---- one (t-block, s-block, head) tile of causal taylor attention ----
__global__ __launch_bounds__(256) void attn_partial(
    const float* __restrict__ QKV, float* __restrict__ numAcc,
    float* __restrict__ denAcc) {
  int p = blockIdx.x;
  const int h = blockIdx.y, tid = threadIdx.x;
  int c = 0;
  while (p >= c + 1) { p -= c + 1; ++c; }
  const int sb = p;
  __shared__ __align__(16) float ql[64 * 17];
  __shared__ __align__(16) float kl[64 * 17];
  __shared__ __align__(16) float vl[64 * 68];
  __shared__ __align__(16) float sc[64 * 68];
  __shared__ __align__(16) float denp[256];
  const int t0 = c * 64, s0 = sb * 64;
  for (int e = tid; e < 1024; e += 256) {
    int t = e >> 4, f = e & 15;
    ql[t * 17 + f] = QKV[(t0 + t) * 1152 + h * 16 + f];
    kl[t * 17 + f] = QKV[(s0 + t) * 1152 + 192 + h * 16 + f];
  }
  for (int e = tid; e < 4096; e += 256) {
    int s = e >> 6, d = e & 63;
    vl[s * 68 + d] = QKV[(s0 + s) * 1152 + 384 + h * 64 + d];
  }
  __syncthreads();
  const bool diag = (sb == c);
  for (int e = tid; e < 4096; e += 256) {
    int t = e >> 6, s = e & 63;
    float val = 0.f;
    if (!diag || s <= t) {
      float qk = 0.f;
#pragma unroll
      for (int f = 0; f < 16; ++f) qk += ql[t * 17 + f] * kl[s * 17 + f];
      val = 1.f + 0.25f * qk + 0.03125f * qk * qk;
    }
    sc[t * 68 + s] = val;
  }
  __syncthreads();
  {
    const int dt = tid & 63, dq = tid >> 6;
    float dpart = 0.f;
    for (int s = dq * 16; s < dq * 16 + 16; ++s) dpart += sc[dt * 68 + s];
    denp[tid] = dpart;
  }
  const int tg = tid >> 4, dg = tid & 15;
  float acc[4][4] = {};
  for (int s4 = 0; s4 < 16; ++s4) {
    float4 srow[4];
#pragma unroll
    for (int i = 0; i < 4; ++i)
      srow[i] = *(const float4*)&sc[(tg * 4 + i) * 68 + s4 * 4];
#pragma unroll
    for (int u = 0; u < 4; ++u) {
      float4 vv = *(const float4*)&vl[(s4 * 4 + u) * 68 + dg * 4];
      float b[4] = {vv.x, vv.y, vv.z, vv.w};
#pragma unroll
      for (int i = 0; i < 4; ++i) {
        float sv = ((const float*)&srow[i])[u];
#pragma unroll
        for (int j = 0; j < 4; ++j) acc[i][j] += sv * b[j];
      }
    }
  }
  __syncthreads();
  if (tid < 64) {
    float d = denp[tid] + denp[tid + 64] + denp[tid + 128] + denp[tid + 192];
    atomicAdd(&denAcc[(t0 + tid) * 12 + h], d);
  }
#pragma unroll
  for (int i = 0; i < 4; ++i) {
    int t = t0 + tg * 4 + i;
#pragma unroll
    for (int j = 0; j < 4; ++j)
      atomicAdd(&numAcc[t * 768 + h * 64 + dg * 4 + j], acc[i][j]);
  }
}

// ---- y = num / (den + eps), emitted as bf16 for the Wo MFMA GEMM ----
__global__ __launch_bounds__(256) void finalize(
    const float* __restrict__ numAcc, const float* __restrict__ denAcc,
    unsigned short* __restrict__ Yb) {
  int g = blockIdx.x * 256 + threadIdx.x;  // float4 index, 98304 total
  int t = g / 192;
  int rem = g - t * 192;
  int h = rem >> 4;
  float4 n = ((const float4*)numAcc)[g];
  float inv = 1.f / (denAcc[t * 12 + h] + 1e-12f);
  ushort4 o;
  o.x = f2bf(n.x * inv); o.y = f2bf(n.y * inv);
  o.z = f2bf(n.z * inv); o.w = f2bf(n.w * inv);
  *(ushort4*)&Yb[g * 4] = o;
}

extern "C" void kernel_launch(void* const* d_in, const int* in_sizes, int n_in,
                              void* d_out, int out_size, void* d_ws, size_t ws_size,
                              hipStream_t stream) {
  const float* hs = (const float*)d_in[0];
  const float* Wq = (const float*)d_in[1];
  const float* Wk = (const float*)d_in[2];
  const float* Wv = (const float*)d_in[3];
  const float* Wo = (const float*)d_in[4];
  float* out = (float*)d_out;
  float* ws = (float*)d_ws;

  float* QKV    = ws;                               // 589824 f
  float* numAcc = ws + 589824;                      // 393216 f
  float* denAcc = ws + 983040;                      // 6144 f
  unsigned short* hsb   = (unsigned short*)(ws + 989184);   // 393216 us
  unsigned short* Wqkvb = (unsigned short*)(ws + 1185792);  // 884736 us
  unsigned short* Wob   = (unsigned short*)(ws + 1628160);  // 589824 us
  unsigned short* Yb    = (unsigned short*)(ws + 1923072);  // 393216 us

  // casts + accumulator zeroing
  prep<<<dim3(2214), 256, 0, stream>>>(hs, Wq, Wk, Wv, Wo, hsb, Wqkvb, Wob, numAcc);
  // QKV = hs @ [Wq|Wk|Wv]^T  -> [512, 1152] fp32
  gemm_mfma<<<dim3(36, 16), 256, 0, stream>>>(hsb, Wqkvb, QKV, 1152, 768);
  // causal taylor attention partials -> numAcc/denAcc
  attn_partial<<<dim3(36, 12), 256, 0, stream>>>(QKV, numAcc, denAcc);
  // y = num/den -> bf16
  finalize<<<dim3(384), 256, 0, stream>>>(numAcc, denAcc, Yb);
  // out = y @ Wo^T
  gemm_mfma<<<dim3(24, 16), 256, 0, stream>>>(Yb, Wob, out, 768, 768);
}

// Round 6
// 119.165 us; speedup vs baseline: 1.8289x; 1.1525x over previous
//
#include <hip/hip_runtime.h>

typedef short bf16x8 __attribute__((ext_vector_type(8)));
typedef float f32x4 __attribute__((ext_vector_type(4)));

__device__ __forceinline__ unsigned short f2bf(float f) {
  union { float f; unsigned int u; } v; v.f = f;
  unsigned int r = v.u + 0x7FFFu + ((v.u >> 16) & 1u);
  return (unsigned short)(r >> 16);
}

// ---- fused: cast hs/Wq/Wk/Wv/Wo to bf16 + zero num/den accumulators ----
__global__ __launch_bounds__(256) void prep(
    const float* __restrict__ hs, const float* __restrict__ Wq,
    const float* __restrict__ Wk, const float* __restrict__ Wv,
    const float* __restrict__ Wo, unsigned short* __restrict__ hsb,
    unsigned short* __restrict__ Wqkvb, unsigned short* __restrict__ Wob,
    float* __restrict__ numAcc) {
  int b = blockIdx.x;
  const float* src; unsigned short* dst; int base;
  if (b < 384)       { src = hs; dst = hsb;            base = b * 1024; }
  else if (b < 528)  { src = Wq; dst = Wqkvb;          base = (b - 384) * 1024; }
  else if (b < 672)  { src = Wk; dst = Wqkvb + 147456; base = (b - 528) * 1024; }
  else if (b < 1248) { src = Wv; dst = Wqkvb + 294912; base = (b - 672) * 1024; }
  else if (b < 1824) { src = Wo; dst = Wob;            base = (b - 1248) * 1024; }
  else {  // zero numAcc(393216) + denAcc(6144) = 99840 float4
    int i = (b - 1824) * 256 + threadIdx.x;
    ((float4*)numAcc)[i] = make_float4(0.f, 0.f, 0.f, 0.f);
    return;
  }
  int i = base + threadIdx.x * 4;
  float4 x = *(const float4*)&src[i];
  ushort4 o;
  o.x = f2bf(x.x); o.y = f2bf(x.y); o.z = f2bf(x.z); o.w = f2bf(x.w);
  *(ushort4*)&dst[i] = o;
}

// ---- QKV GEMM: C[M,N](bf16) = A[M,K]bf16 @ B[N,K]^T bf16, MFMA 16x16x32 ----
__global__ __launch_bounds__(256) void gemm_qkv(
    const unsigned short* __restrict__ A, const unsigned short* __restrict__ B,
    unsigned short* __restrict__ C, int N, int K) {
  const int tid = threadIdx.x;
  const int w = tid >> 6, lane = tid & 63;
  const int lm = lane & 15, quad = lane >> 4;
  const int mt = blockIdx.y * 32 + (w >> 1) * 16;
  const int nt = blockIdx.x * 32 + (w & 1) * 16;
  const unsigned short* a_ptr = A + (mt + lm) * K + quad * 8;
  const unsigned short* b_ptr = B + (nt + lm) * K + quad * 8;
  f32x4 acc = {0.f, 0.f, 0.f, 0.f};
#pragma unroll 4
  for (int kb = 0; kb < K; kb += 32) {
    bf16x8 av = *(const bf16x8*)(a_ptr + kb);
    bf16x8 bv = *(const bf16x8*)(b_ptr + kb);
    acc = __builtin_amdgcn_mfma_f32_16x16x32_bf16(av, bv, acc, 0, 0, 0);
  }
#pragma unroll
  for (int r = 0; r < 4; ++r)
    C[(mt + quad * 4 + r) * N + nt + lm] = f2bf(acc[r]);
}

// ---- MFMA causal taylor attention: one (t-blk, s-blk, head) per block ----
__global__ __launch_bounds__(256) void attn_mfma(
    const unsigned short* __restrict__ QKVb, float* __restrict__ numAcc,
    float* __restrict__ denAcc) {
  int p = blockIdx.x;
  const int h = blockIdx.y, tid = threadIdx.x;
  int c = 0;
  while (p >= c + 1) { p -= c + 1; ++c; }
  const int sb = p;
  const int t0 = c * 64, s0 = sb * 64;
  __shared__ __align__(16) unsigned short Vt[64 * 72];   // [d][s] transposed
  __shared__ __align__(16) unsigned short scl[64 * 72];  // [t][s] bf16 scores
  __shared__ float denb[64];
  const int w = tid >> 6, lane = tid & 63;
  const int lm = lane & 15, quad = lane >> 4;
  // stage V transposed: [s][d] global -> Vt[d][s]
#pragma unroll
  for (int pp = 0; pp < 2; ++pp) {
    int idx = pp * 256 + tid;
    int s = idx >> 3, c8 = (idx & 7) * 8;
    bf16x8 v = *(const bf16x8*)&QKVb[(s0 + s) * 1152 + 384 + h * 64 + c8];
#pragma unroll
    for (int j = 0; j < 8; ++j) Vt[(c8 + j) * 72 + s] = ((unsigned short*)&v)[j];
  }
  // scores: wave w owns t-rows [w*16, w*16+16); 4 s-tiles of 16
  bf16x8 aq = {0, 0, 0, 0, 0, 0, 0, 0};
  if (quad < 2)
    aq = *(const bf16x8*)&QKVb[(t0 + w * 16 + lm) * 1152 + h * 16 + quad * 8];
  f32x4 qk[4];
#pragma unroll
  for (int sbt = 0; sbt < 4; ++sbt) {
    bf16x8 bk = {0, 0, 0, 0, 0, 0, 0, 0};
    if (quad < 2)
      bk = *(const bf16x8*)&QKVb[(s0 + sbt * 16 + lm) * 1152 + 192 + h * 16 + quad * 8];
    f32x4 z = {0.f, 0.f, 0.f, 0.f};
    qk[sbt] = __builtin_amdgcn_mfma_f32_16x16x32_bf16(aq, bk, z, 0, 0, 0);
  }
  // poly + causal mask; den row-partials via lm-butterfly; sc -> LDS bf16
  float dsum[4] = {0.f, 0.f, 0.f, 0.f};  // per r (t-row = w*16+quad*4+r)
#pragma unroll
  for (int sbt = 0; sbt < 4; ++sbt) {
#pragma unroll
    for (int r = 0; r < 4; ++r) {
      int tl = w * 16 + quad * 4 + r;
      int sl = sbt * 16 + lm;
      float x = qk[sbt][r];
      float val = (s0 + sl <= t0 + tl) ? 1.f + 0.25f * x + 0.03125f * x * x : 0.f;
      dsum[r] += val;
      scl[tl * 72 + sl] = f2bf(val);
    }
  }
#pragma unroll
  for (int r = 0; r < 4; ++r) {
    float v = dsum[r];
    v += __shfl_xor(v, 1); v += __shfl_xor(v, 2);
    v += __shfl_xor(v, 4); v += __shfl_xor(v, 8);
    if (lm == 0) denb[w * 16 + quad * 4 + r] = v;
  }
  __syncthreads();
  // AV: wave w rows t=[w*16,+16); 4 d-tiles x (k=64 -> 2 MFMAs)
  f32x4 av[4] = {{0.f,0.f,0.f,0.f},{0.f,0.f,0.f,0.f},{0.f,0.f,0.f,0.f},{0.f,0.f,0.f,0.f}};
#pragma unroll
  for (int kb = 0; kb < 2; ++kb) {
    bf16x8 a = *(const bf16x8*)&scl[(w * 16 + lm) * 72 + kb * 32 + quad * 8];
#pragma unroll
    for (int dt = 0; dt < 4; ++dt) {
      bf16x8 b = *(const bf16x8*)&Vt[(dt * 16 + lm) * 72 + kb * 32 + quad * 8];
      av[dt] = __builtin_amdgcn_mfma_f32_16x16x32_bf16(a, b, av[dt], 0, 0, 0);
    }
  }
  // accumulate
  if (tid < 64) atomicAdd(&denAcc[(t0 + tid) * 12 + h], denb[tid]);
#pragma unroll
  for (int dt = 0; dt < 4; ++dt)
#pragma unroll
    for (int r = 0; r < 4; ++r)
      atomicAdd(&numAcc[(t0 + w * 16 + quad * 4 + r) * 768 + h * 64 + dt * 16 + lm],
                av[dt][r]);
}

// ---- out GEMM with fused y = num/den: out = (num/den) @ Wo^T, fp32 out ----
__global__ __launch_bounds__(256) void gemm_out(
    const float* __restrict__ numAcc, const float* __restrict__ denAcc,
    const unsigned short* __restrict__ B, float* __restrict__ out) {
  const int tid = threadIdx.x;
  const int w = tid >> 6, lane = tid & 63;
  const int lm = lane & 15, quad = lane >> 4;
  const int mt = blockIdx.y * 32 + (w >> 1) * 16;
  const int nt = blockIdx.x * 32 + (w & 1) * 16;
  const int t = mt + lm;
  f32x4 acc = {0.f, 0.f, 0.f, 0.f};
#pragma unroll 4
  for (int kb = 0; kb < 768; kb += 32) {
    int k0 = kb + quad * 8;
    float inv = 1.f / (denAcc[t * 12 + (k0 >> 6)] + 1e-12f);
    float4 n0 = *(const float4*)&numAcc[t * 768 + k0];
    float4 n1 = *(const float4*)&numAcc[t * 768 + k0 + 4];
    bf16x8 a;
    a[0] = f2bf(n0.x * inv); a[1] = f2bf(n0.y * inv);
    a[2] = f2bf(n0.z * inv); a[3] = f2bf(n0.w * inv);
    a[4] = f2bf(n1.x * inv); a[5] = f2bf(n1.y * inv);
    a[6] = f2bf(n1.z * inv); a[7] = f2bf(n1.w * inv);
    bf16x8 bv = *(const bf16x8*)&B[(nt + lm) * 768 + k0];
    acc = __builtin_amdgcn_mfma_f32_16x16x32_bf16(a, bv, acc, 0, 0, 0);
  }
#pragma unroll
  for (int r = 0; r < 4; ++r)
    out[(mt + quad * 4 + r) * 768 + nt + lm] = acc[r];
}

extern "C" void kernel_launch(void* const* d_in, const int* in_sizes, int n_in,
                              void* d_out, int out_size, void* d_ws, size_t ws_size,
                              hipStream_t stream) {
  const float* hs = (const float*)d_in[0];
  const float* Wq = (const float*)d_in[1];
  const float* Wk = (const float*)d_in[2];
  const float* Wv = (const float*)d_in[3];
  const float* Wo = (const float*)d_in[4];
  float* out = (float*)d_out;
  float* ws = (float*)d_ws;

  float* numAcc = ws;                                       // 393216 f
  float* denAcc = ws + 393216;                              // 6144 f
  unsigned short* hsb   = (unsigned short*)(ws + 399360);   // 393216 us
  unsigned short* Wqkvb = hsb + 393216;                     // 884736 us
  unsigned short* Wob   = Wqkvb + 884736;                   // 589824 us
  unsigned short* QKVb  = Wob + 589824;                     // 589824 us

  // casts + accumulator zeroing
  prep<<<dim3(2214), 256, 0, stream>>>(hs, Wq, Wk, Wv, Wo, hsb, Wqkvb, Wob, numAcc);
  // QKV(bf16) = hs @ [Wq|Wk|Wv]^T  -> [512, 1152]
  gemm_qkv<<<dim3(36, 16), 256, 0, stream>>>(hsb, Wqkvb, QKVb, 1152, 768);
  // MFMA causal taylor attention partials -> numAcc/denAcc
  attn_mfma<<<dim3(36, 12), 256, 0, stream>>>(QKVb, numAcc, denAcc);
  // out = (num/den) @ Wo^T
  gemm_out<<<dim3(24, 16), 256, 0, stream>>>(numAcc, denAcc, Wob, out);
}

// Round 7
// 109.342 us; speedup vs baseline: 1.9932x; 1.0898x over previous
//
#include <hip/hip_runtime.h>

typedef short bf16x8 __attribute__((ext_vector_type(8)));
typedef float f32x4 __attribute__((ext_vector_type(4)));

__device__ __forceinline__ unsigned short f2bf(float f) {
  union { float f; unsigned int u; } v; v.f = f;
  unsigned int r = v.u + 0x7FFFu + ((v.u >> 16) & 1u);
  return (unsigned short)(r >> 16);
}

// ---- fused: cast hs/Wq/Wk/Wv/Wo to bf16 + zero num/den accumulators ----
__global__ __launch_bounds__(256) void prep(
    const float* __restrict__ hs, const float* __restrict__ Wq,
    const float* __restrict__ Wk, const float* __restrict__ Wv,
    const float* __restrict__ Wo, unsigned short* __restrict__ hsb,
    unsigned short* __restrict__ Wqkvb, unsigned short* __restrict__ Wob,
    float* __restrict__ numAcc) {
  int b = blockIdx.x;
  const float* src; unsigned short* dst; int base;
  if (b < 384)       { src = hs; dst = hsb;            base = b * 1024; }
  else if (b < 528)  { src = Wq; dst = Wqkvb;          base = (b - 384) * 1024; }
  else if (b < 672)  { src = Wk; dst = Wqkvb + 147456; base = (b - 528) * 1024; }
  else if (b < 1248) { src = Wv; dst = Wqkvb + 294912; base = (b - 672) * 1024; }
  else if (b < 1824) { src = Wo; dst = Wob;            base = (b - 1248) * 1024; }
  else {  // zero numAcc(393216) + denAcc(6144) = 99840 float4
    int i = (b - 1824) * 256 + threadIdx.x;
    ((float4*)numAcc)[i] = make_float4(0.f, 0.f, 0.f, 0.f);
    return;
  }
  int i = base + threadIdx.x * 4;
  float4 x = *(const float4*)&src[i];
  ushort4 o;
  o.x = f2bf(x.x); o.y = f2bf(x.y); o.z = f2bf(x.z); o.w = f2bf(x.w);
  *(ushort4*)&dst[i] = o;
}

// ---- QKV GEMM, split-K x4: one block per 16x16 tile, 4 waves over K ----
__global__ __launch_bounds__(256) void gemm_qkv(
    const unsigned short* __restrict__ A, const unsigned short* __restrict__ B,
    unsigned short* __restrict__ C, int N, int K) {
  __shared__ f32x4 part[4][64];
  const int tid = threadIdx.x;
  const int w = tid >> 6, lane = tid & 63;
  const int lm = lane & 15, quad = lane >> 4;
  const int mt = blockIdx.y * 16;
  const int nt = blockIdx.x * 16;
  const int kw = w * (K >> 2);
  const unsigned short* a_ptr = A + (mt + lm) * K + kw + quad * 8;
  const unsigned short* b_ptr = B + (nt + lm) * K + kw + quad * 8;
  f32x4 acc = {0.f, 0.f, 0.f, 0.f};
#pragma unroll
  for (int kb = 0; kb < 192; kb += 32) {
    bf16x8 av = *(const bf16x8*)(a_ptr + kb);
    bf16x8 bv = *(const bf16x8*)(b_ptr + kb);
    acc = __builtin_amdgcn_mfma_f32_16x16x32_bf16(av, bv, acc, 0, 0, 0);
  }
  part[w][lane] = acc;
  __syncthreads();
  if (w == 0) {
    f32x4 s = part[0][lane] + part[1][lane] + part[2][lane] + part[3][lane];
#pragma unroll
    for (int r = 0; r < 4; ++r)
      C[(mt + quad * 4 + r) * N + nt + lm] = f2bf(s[r]);
  }
}

// ---- MFMA causal taylor attention: one (t-blk, s-blk, head) per block ----
__global__ __launch_bounds__(256) void attn_mfma(
    const unsigned short* __restrict__ QKVb, float* __restrict__ numAcc,
    float* __restrict__ denAcc) {
  int p = blockIdx.x;
  const int h = blockIdx.y, tid = threadIdx.x;
  int c = 0;
  while (p >= c + 1) { p -= c + 1; ++c; }
  const int sb = p;
  const int t0 = c * 64, s0 = sb * 64;
  __shared__ __align__(16) unsigned short Vt[64 * 72];   // [d][s] transposed
  __shared__ __align__(16) unsigned short scl[64 * 72];  // [t][s] bf16 scores
  __shared__ float denb[64];
  const int w = tid >> 6, lane = tid & 63;
  const int lm = lane & 15, quad = lane >> 4;
  // stage V transposed: [s][d] global -> Vt[d][s]
#pragma unroll
  for (int pp = 0; pp < 2; ++pp) {
    int idx = pp * 256 + tid;
    int s = idx >> 3, c8 = (idx & 7) * 8;
    bf16x8 v = *(const bf16x8*)&QKVb[(s0 + s) * 1152 + 384 + h * 64 + c8];
#pragma unroll
    for (int j = 0; j < 8; ++j) Vt[(c8 + j) * 72 + s] = ((unsigned short*)&v)[j];
  }
  // scores: wave w owns t-rows [w*16, w*16+16); 4 s-tiles of 16
  bf16x8 aq = {0, 0, 0, 0, 0, 0, 0, 0};
  if (quad < 2)
    aq = *(const bf16x8*)&QKVb[(t0 + w * 16 + lm) * 1152 + h * 16 + quad * 8];
  f32x4 qk[4];
#pragma unroll
  for (int sbt = 0; sbt < 4; ++sbt) {
    bf16x8 bk = {0, 0, 0, 0, 0, 0, 0, 0};
    if (quad < 2)
      bk = *(const bf16x8*)&QKVb[(s0 + sbt * 16 + lm) * 1152 + 192 + h * 16 + quad * 8];
    f32x4 z = {0.f, 0.f, 0.f, 0.f};
    qk[sbt] = __builtin_amdgcn_mfma_f32_16x16x32_bf16(aq, bk, z, 0, 0, 0);
  }
  // poly + causal mask; den row-partials via lm-butterfly; sc -> LDS bf16
  float dsum[4] = {0.f, 0.f, 0.f, 0.f};
#pragma unroll
  for (int sbt = 0; sbt < 4; ++sbt) {
#pragma unroll
    for (int r = 0; r < 4; ++r) {
      int tl = w * 16 + quad * 4 + r;
      int sl = sbt * 16 + lm;
      float x = qk[sbt][r];
      float val = (s0 + sl <= t0 + tl) ? 1.f + 0.25f * x + 0.03125f * x * x : 0.f;
      dsum[r] += val;
      scl[tl * 72 + sl] = f2bf(val);
    }
  }
#pragma unroll
  for (int r = 0; r < 4; ++r) {
    float v = dsum[r];
    v += __shfl_xor(v, 1); v += __shfl_xor(v, 2);
    v += __shfl_xor(v, 4); v += __shfl_xor(v, 8);
    if (lm == 0) denb[w * 16 + quad * 4 + r] = v;
  }
  __syncthreads();
  // AV: wave w rows t=[w*16,+16); 4 d-tiles x (k=64 -> 2 MFMAs)
  f32x4 av[4] = {{0.f,0.f,0.f,0.f},{0.f,0.f,0.f,0.f},{0.f,0.f,0.f,0.f},{0.f,0.f,0.f,0.f}};
#pragma unroll
  for (int kb = 0; kb < 2; ++kb) {
    bf16x8 a = *(const bf16x8*)&scl[(w * 16 + lm) * 72 + kb * 32 + quad * 8];
#pragma unroll
    for (int dt = 0; dt < 4; ++dt) {
      bf16x8 b = *(const bf16x8*)&Vt[(dt * 16 + lm) * 72 + kb * 32 + quad * 8];
      av[dt] = __builtin_amdgcn_mfma_f32_16x16x32_bf16(a, b, av[dt], 0, 0, 0);
    }
  }
  // accumulate
  if (tid < 64) atomicAdd(&denAcc[(t0 + tid) * 12 + h], denb[tid]);
#pragma unroll
  for (int dt = 0; dt < 4; ++dt)
#pragma unroll
    for (int r = 0; r < 4; ++r)
      atomicAdd(&numAcc[(t0 + w * 16 + quad * 4 + r) * 768 + h * 64 + dt * 16 + lm],
                av[dt][r]);
}

// ---- out GEMM, split-K x4, fused y = num/den on the A-fragment ----
__global__ __launch_bounds__(256) void gemm_out(
    const float* __restrict__ numAcc, const float* __restrict__ denAcc,
    const unsigned short* __restrict__ B, float* __restrict__ out) {
  __shared__ f32x4 part[4][64];
  const int tid = threadIdx.x;
  const int w = tid >> 6, lane = tid & 63;
  const int lm = lane & 15, quad = lane >> 4;
  const int mt = blockIdx.y * 16;
  const int nt = blockIdx.x * 16;
  const int t = mt + lm;
  const int kw = w * 192;
  f32x4 acc = {0.f, 0.f, 0.f, 0.f};
#pragma unroll
  for (int kb = 0; kb < 192; kb += 32) {
    int k0 = kw + kb + quad * 8;
    float inv = 1.f / (denAcc[t * 12 + (k0 >> 6)] + 1e-12f);
    float4 n0 = *(const float4*)&numAcc[t * 768 + k0];
    float4 n1 = *(const float4*)&numAcc[t * 768 + k0 + 4];
    bf16x8 a;
    a[0] = f2bf(n0.x * inv); a[1] = f2bf(n0.y * inv);
    a[2] = f2bf(n0.z * inv); a[3] = f2bf(n0.w * inv);
    a[4] = f2bf(n1.x * inv); a[5] = f2bf(n1.y * inv);
    a[6] = f2bf(n1.z * inv); a[7] = f2bf(n1.w * inv);
    bf16x8 bv = *(const bf16x8*)&B[(nt + lm) * 768 + k0];
    acc = __builtin_amdgcn_mfma_f32_16x16x32_bf16(a, bv, acc, 0, 0, 0);
  }
  part[w][lane] = acc;
  __syncthreads();
  if (w == 0) {
    f32x4 s = part[0][lane] + part[1][lane] + part[2][lane] + part[3][lane];
#pragma unroll
    for (int r = 0; r < 4; ++r)
      out[(mt + quad * 4 + r) * 768 + nt + lm] = s[r];
  }
}

extern "C" void kernel_launch(void* const* d_in, const int* in_sizes, int n_in,
                              void* d_out, int out_size, void* d_ws, size_t ws_size,
                              hipStream_t stream) {
  const float* hs = (const float*)d_in[0];
  const float* Wq = (const float*)d_in[1];
  const float* Wk = (const float*)d_in[2];
  const float* Wv = (const float*)d_in[3];
  const float* Wo = (const float*)d_in[4];
  float* out = (float*)d_out;
  float* ws = (float*)d_ws;

  float* numAcc = ws;                                       // 393216 f
  float* denAcc = ws + 393216;                              // 6144 f
  unsigned short* hsb   = (unsigned short*)(ws + 399360);   // 393216 us
  unsigned short* Wqkvb = hsb + 393216;                     // 884736 us
  unsigned short* Wob   = Wqkvb + 884736;                   // 589824 us
  unsigned short* QKVb  = Wob + 589824;                     // 589824 us

  // casts + accumulator zeroing
  prep<<<dim3(2214), 256, 0, stream>>>(hs, Wq, Wk, Wv, Wo, hsb, Wqkvb, Wob, numAcc);
  // QKV(bf16) = hs @ [Wq|Wk|Wv]^T  -> [512, 1152], split-K
  gemm_qkv<<<dim3(72, 32), 256, 0, stream>>>(hsb, Wqkvb, QKVb, 1152, 768);
  // MFMA causal taylor attention partials -> numAcc/denAcc
  attn_mfma<<<dim3(36, 12), 256, 0, stream>>>(QKVb, numAcc, denAcc);
  // out = (num/den) @ Wo^T, split-K
  gemm_out<<<dim3(48, 32), 256, 0, stream>>>(numAcc, denAcc, Wob, out);
}